// Round 1
// baseline (170.314 us; speedup 1.0000x reference)
//
#include <hip/hip_runtime.h>

// Problem: B=8, T=S=512, M=N=512, H=128
// score[b,t,s] = (1/sqrt(512)) * sum_h v[h] * tanh(x1[b,t,h] + x2[b,s,h])
//   x1 = query @ W2, x2 = keys @ W1
// Fold: tanh(x) = 1 - 2/(exp2(2*log2e*x)+1)
//   => score = (Sv - 2*sum_h v[h]/(exp2(x1s+x2s)+1)) / SCALE,  Sv = sum_h v[h]
// where x1s/x2s are pre-scaled by 2*log2e in the projection kernel.

constexpr float SCALE_IN  = 2.8853900817779268f;   // 2*log2(e)
constexpr float INV_SCALE = 0.04419417382415922f;  // 1/sqrt(512)

// ---------------- Projection GEMMs: (4096x512)@(512x128), twice --------------
// Block = 512 threads: h = tid&127 (lane-coalesced over W/out), rg = tid>>7.
// Each thread: 8 rows register-blocked; A-row loads are wave-uniform -> scalar.
__global__ __launch_bounds__(512) void proj_kernel(
    const float* __restrict__ q,  const float* __restrict__ w2,
    const float* __restrict__ kk, const float* __restrict__ w1,
    float* __restrict__ x1w, float* __restrict__ x2w) {
  int blk = blockIdx.x;                 // 0..255 ; first 128 -> x1, rest -> x2
  const float* A; const float* W; float* O;
  if (blk < 128) { A = q;  W = w2; O = x1w; }
  else           { blk -= 128; A = kk; W = w1; O = x2w; }

  const int tid = threadIdx.x;
  const int h   = tid & 127;
  const int rg  = tid >> 7;                       // 0..3 (uniform per wave)
  const int rbase = __builtin_amdgcn_readfirstlane(blk * 32 + rg * 8);

  float acc[8];
#pragma unroll
  for (int r = 0; r < 8; ++r) acc[r] = 0.0f;

  for (int m = 0; m < 512; m += 4) {
    const float wa = W[(m + 0) * 128 + h];
    const float wb = W[(m + 1) * 128 + h];
    const float wc = W[(m + 2) * 128 + h];
    const float wd = W[(m + 3) * 128 + h];
#pragma unroll
    for (int r = 0; r < 8; ++r) {
      const float4 a = *(const float4*)(A + (rbase + r) * 512 + m);
      acc[r] = fmaf(a.x, wa, acc[r]);
      acc[r] = fmaf(a.y, wb, acc[r]);
      acc[r] = fmaf(a.z, wc, acc[r]);
      acc[r] = fmaf(a.w, wd, acc[r]);
    }
  }
#pragma unroll
  for (int r = 0; r < 8; ++r)
    O[(rbase + r) * 128 + h] = acc[r] * SCALE_IN;  // pre-scale by 2*log2e
}

// ---------------- Main score kernel -----------------------------------------
// Grid: 512 blocks = 8 batches x (8x8) tiles of 64x64 (t,s).
// LDS holds h-major transposed tiles: x1l[h][t], x2l[h][s] (64-float rows).
// Thread: tg = tid>>4 -> 4 t's, sg = tid&15 -> 4 s's (s fastest -> coalesced
// float4 stores). Per h: 2x ds_read_b128 + 16 x (add, exp2, add, rcp, fma).
__global__ __launch_bounds__(256) void score_kernel(
    const float* __restrict__ x1w, const float* __restrict__ x2w,
    const float* __restrict__ v, float* __restrict__ out) {
  __shared__ float x1l[128 * 64];
  __shared__ float x2l[128 * 64];
  __shared__ float vl[128];

  const int tid   = threadIdx.x;
  const int b     = blockIdx.x >> 6;
  const int tile  = blockIdx.x & 63;
  const int tbase = (tile >> 3) * 64;
  const int sbase = (tile & 7) * 64;

  const float4* x1g = (const float4*)(x1w + (b * 512 + tbase) * 128);
  const float4* x2g = (const float4*)(x2w + (b * 512 + sbase) * 128);

  if (tid < 32) ((float4*)vl)[tid] = ((const float4*)v)[tid];

  // Transposed staging: row distinct across lanes -> conflict-free ds_write.
  const int l  = tid & 63;
  const int wv = tid >> 6;
#pragma unroll
  for (int p = 0; p < 8; ++p) {
    const int row = (l & 31) + 32 * (p & 1);            // t (or s) index 0..63
    const int c4  = (l >> 5) + 2 * wv + 8 * (p >> 1);   // h/4 index 0..31
    const float4 a = x1g[row * 32 + c4];
    x1l[(4 * c4 + 0) * 64 + row] = a.x;
    x1l[(4 * c4 + 1) * 64 + row] = a.y;
    x1l[(4 * c4 + 2) * 64 + row] = a.z;
    x1l[(4 * c4 + 3) * 64 + row] = a.w;
    const float4 c = x2g[row * 32 + c4];
    x2l[(4 * c4 + 0) * 64 + row] = c.x;
    x2l[(4 * c4 + 1) * 64 + row] = c.y;
    x2l[(4 * c4 + 2) * 64 + row] = c.z;
    x2l[(4 * c4 + 3) * 64 + row] = c.w;
  }
  __syncthreads();

  const int sg = tid & 15;   // s fast -> coalesced stores
  const int tg = tid >> 4;

  float racc[16];
#pragma unroll
  for (int i = 0; i < 16; ++i) racc[i] = 0.0f;
  float sv = 0.0f;

#pragma unroll 4
  for (int h = 0; h < 128; ++h) {
    const float4 tf = *(const float4*)(x1l + h * 64 + 4 * tg);
    const float4 sf = *(const float4*)(x2l + h * 64 + 4 * sg);
    const float vh = vl[h];
    sv += vh;
    const float ts[4] = {tf.x, tf.y, tf.z, tf.w};
    const float ss[4] = {sf.x, sf.y, sf.z, sf.w};
#pragma unroll
    for (int i = 0; i < 4; ++i) {
#pragma unroll
      for (int j = 0; j < 4; ++j) {
        const float e = __builtin_amdgcn_exp2f(ts[i] + ss[j]);
        const float r = __builtin_amdgcn_rcpf(e + 1.0f);
        racc[i * 4 + j] = fmaf(vh, r, racc[i * 4 + j]);
      }
    }
  }

  const float c1 = sv * INV_SCALE;            // sum_h v[h] / SCALE
  const float c2 = -2.0f * INV_SCALE;
#pragma unroll
  for (int i = 0; i < 4; ++i) {
    const int t = tbase + 4 * tg + i;
    float4 o;
    o.x = fmaf(racc[i * 4 + 0], c2, c1);
    o.y = fmaf(racc[i * 4 + 1], c2, c1);
    o.z = fmaf(racc[i * 4 + 2], c2, c1);
    o.w = fmaf(racc[i * 4 + 3], c2, c1);
    *(float4*)(out + (size_t)(b * 512 + t) * 512 + sbase + 4 * sg) = o;
  }
}

extern "C" void kernel_launch(void* const* d_in, const int* in_sizes, int n_in,
                              void* d_out, int out_size, void* d_ws, size_t ws_size,
                              hipStream_t stream) {
  const float* query = (const float*)d_in[0];  // (8,512,512)
  const float* keys  = (const float*)d_in[1];  // (8,512,512)
  const float* W1    = (const float*)d_in[2];  // (512,128) pairs with keys
  const float* W2    = (const float*)d_in[3];  // (512,128) pairs with query
  const float* v     = (const float*)d_in[4];  // (128,)
  float* out = (float*)d_out;                  // (8,512,512) fp32

  float* x1w = (float*)d_ws;                   // 8*512*128 floats (2 MB)
  float* x2w = x1w + 8 * 512 * 128;            // 2 MB more

  hipLaunchKernelGGL(proj_kernel, dim3(256), dim3(512), 0, stream,
                     query, W2, keys, W1, x1w, x2w);
  hipLaunchKernelGGL(score_kernel, dim3(512), dim3(256), 0, stream,
                     x1w, x2w, v, out);
}

// Round 2
// 145.650 us; speedup vs baseline: 1.1693x; 1.1693x over previous
//
#include <hip/hip_runtime.h>
#include <hip/hip_fp16.h>

// B=8, T=S=512, M=N=512, H=128
// score[b,t,s] = (1/sqrt(512)) * sum_h v[h]*tanh(x1[b,t,h]+x2[b,s,h])
// tanh(x) = 1 - 2/(1+e^{2x}) => score = (Sv - 2*sum_h v_h*sigma_h)/SCALE,
//   sigma = 1/(1+e), e = exp2(z), z = 2*log2e*x, x = x1+x2.
// proj stores exp2(z1) factored as (half em, int16 k): exp2(z1)=em*2^k,
// so e = (em_t*em_s)*2^(k_t+k_s)  -> mul+add+ldexp, no exp2 in the hot loop.
// 4-way rcp merge: v1/a1+..+v4/a4 = num/(a1a2a3a4), one rcp per 4 elements.

constexpr float SCALE_IN  = 2.8853900817779268f;   // 2*log2(e)
constexpr float INV_SCALE = 0.04419417382415922f;  // 1/sqrt(512)

// ---------------- Projection GEMM + exp-factor pack --------------------------
// Grid 256 blocks (128 per matrix), 512 threads. Block: 32 rows x 128 h.
// LDS: A-tile 32x64 (8KB) + W-tile 64x128 (32KB). Thread: 2 rows x 4 h.
__global__ __launch_bounds__(512) void proj_kernel(
    const float* __restrict__ q,  const float* __restrict__ w2,
    const float* __restrict__ ky, const float* __restrict__ w1,
    unsigned int* __restrict__ x1w, unsigned int* __restrict__ x2w) {
  __shared__ float As[32 * 64];    // [row][k]
  __shared__ float Ws[64 * 128];   // [k][h]

  int blk = blockIdx.x;
  const float* A; const float* W; unsigned int* O;
  if (blk < 128) { A = q;  W = w2; O = x1w; }
  else           { blk -= 128; A = ky; W = w1; O = x2w; }
  const int rbase = blk * 32;
  const int tid = threadIdx.x;

  const int rq = tid >> 5;          // 0..15 -> rows 2*rq+{0,1}
  const int hq = tid & 31;          // h = 4*hq+{0..3}

  float acc[2][4];
#pragma unroll
  for (int r = 0; r < 2; ++r)
#pragma unroll
    for (int c = 0; c < 4; ++c) acc[r][c] = 0.0f;

  for (int kb = 0; kb < 512; kb += 64) {
    // stage A: 2048 floats, 1 float4/thread (coalesced 16-lane rows)
    {
      const int arow = tid >> 4;          // 0..31
      const int kq4  = (tid & 15) * 4;
      *(float4*)(As + arow * 64 + kq4) =
          *(const float4*)(A + (size_t)(rbase + arow) * 512 + kb + kq4);
      // stage W: 8192 floats, 4 float4/thread (coalesced 32-lane rows)
      const int wrow = tid >> 5;          // 0..15
      const int hq4  = (tid & 31) * 4;
#pragma unroll
      for (int p = 0; p < 4; ++p)
        *(float4*)(Ws + (wrow + 16 * p) * 128 + hq4) =
            *(const float4*)(W + (size_t)(kb + wrow + 16 * p) * 128 + hq4);
    }
    __syncthreads();
#pragma unroll 4
    for (int k4 = 0; k4 < 64; k4 += 4) {
      float a[2][4], w[4][4];
      *(float4*)a[0] = *(const float4*)(As + (2 * rq + 0) * 64 + k4);
      *(float4*)a[1] = *(const float4*)(As + (2 * rq + 1) * 64 + k4);
#pragma unroll
      for (int kk = 0; kk < 4; ++kk)
        *(float4*)w[kk] = *(const float4*)(Ws + (k4 + kk) * 128 + 4 * hq);
#pragma unroll
      for (int kk = 0; kk < 4; ++kk)
#pragma unroll
        for (int r = 0; r < 2; ++r)
#pragma unroll
          for (int c = 0; c < 4; ++c)
            acc[r][c] = fmaf(a[r][kk], w[kk][c], acc[r][c]);
    }
    __syncthreads();
  }

  // epilogue: z = acc*2log2e ; exp2(z) = em * 2^k ; pack (k<<16)|half(em)
#pragma unroll
  for (int r = 0; r < 2; ++r) {
    unsigned int pk[4];
#pragma unroll
    for (int c = 0; c < 4; ++c) {
      const float z  = acc[r][c] * SCALE_IN;
      const float kf = rintf(z);
      const int   ki = (int)kf;
      const float em = __builtin_amdgcn_exp2f(z - kf);   // in [0.707,1.414]
      const __half hh = __float2half_rn(em);
      pk[c] = ((unsigned int)ki << 16) | (unsigned int)__half_as_ushort(hh);
    }
    *(uint4*)(O + (size_t)(rbase + 2 * rq + r) * 128 + 4 * hq) = *(uint4*)pk;
  }
}

// ---------------- Main score kernel -----------------------------------------
// 512 blocks x 512 threads. Tile 64(t) x 64(s). LDS: packed [h][row], 64KB.
// Thread: 2 t x 4 s. Per h-group of 4: e_i = ldexp(emt*ems, min(kt+ks,30)),
// a_i=e_i+1, racc += (v1a2+v2a1)p34+(v3a4+v4a3)p12) * rcp(p12*p34).
__global__ __launch_bounds__(512) void score_kernel(
    const unsigned int* __restrict__ x1w, const unsigned int* __restrict__ x2w,
    const float* __restrict__ v, float* __restrict__ out) {
  __shared__ unsigned int x1l[128 * 64];  // [h][t]
  __shared__ unsigned int x2l[128 * 64];  // [h][s]

  const int tid   = threadIdx.x;
  const int b     = blockIdx.x >> 6;
  const int tile  = blockIdx.x & 63;
  const int tbase = (tile >> 3) * 64;
  const int sbase = (tile & 7) * 64;

  const uint4* x1g = (const uint4*)(x1w + (b * 512 + tbase) * 128);
  const uint4* x2g = (const uint4*)(x2w + (b * 512 + sbase) * 128);

  // transposed staging: rows distinct across lanes -> conflict-free (2-way max)
  const int l  = tid & 63;
  const int wq = tid >> 6;                              // 0..7
#pragma unroll
  for (int p = 0; p < 4; ++p) {
    const int row = (l & 31) + 32 * (p & 1);
    const int c4  = (l >> 5) + 2 * wq + 16 * (p >> 1);  // 0..31
    const uint4 a = x1g[row * 32 + c4];
    x1l[(4 * c4 + 0) * 64 + row] = a.x;
    x1l[(4 * c4 + 1) * 64 + row] = a.y;
    x1l[(4 * c4 + 2) * 64 + row] = a.z;
    x1l[(4 * c4 + 3) * 64 + row] = a.w;
    const uint4 c = x2g[row * 32 + c4];
    x2l[(4 * c4 + 0) * 64 + row] = c.x;
    x2l[(4 * c4 + 1) * 64 + row] = c.y;
    x2l[(4 * c4 + 2) * 64 + row] = c.z;
    x2l[(4 * c4 + 3) * 64 + row] = c.w;
  }
  __syncthreads();

  const int sg = tid & 15;   // s = 4*sg+j (coalesced stores)
  const int tg = tid >> 4;   // 0..31, t = 2*tg+i

  float racc[2][4];
#pragma unroll
  for (int i = 0; i < 2; ++i)
#pragma unroll
    for (int j = 0; j < 4; ++j) racc[i][j] = 0.0f;
  float sv = 0.0f;

  for (int hg = 0; hg < 32; ++hg) {
    const int h0 = hg * 4;
    const float4 vq = *(const float4*)(v + h0);  // uniform -> s_load
    sv += (vq.x + vq.y) + (vq.z + vq.w);

    float emt[2][4]; int kt[2][4];
    float ems[4][4]; int ks[4][4];
#pragma unroll
    for (int qq = 0; qq < 4; ++qq) {
      const uint2 tp = *(const uint2*)(x1l + (h0 + qq) * 64 + 2 * tg);
      emt[0][qq] = __half2float(__ushort_as_half((unsigned short)tp.x));
      kt [0][qq] = ((int)tp.x) >> 16;
      emt[1][qq] = __half2float(__ushort_as_half((unsigned short)tp.y));
      kt [1][qq] = ((int)tp.y) >> 16;
      const uint4 sp = *(const uint4*)(x2l + (h0 + qq) * 64 + 4 * sg);
      ems[0][qq] = __half2float(__ushort_as_half((unsigned short)sp.x));
      ks [0][qq] = ((int)sp.x) >> 16;
      ems[1][qq] = __half2float(__ushort_as_half((unsigned short)sp.y));
      ks [1][qq] = ((int)sp.y) >> 16;
      ems[2][qq] = __half2float(__ushort_as_half((unsigned short)sp.z));
      ks [2][qq] = ((int)sp.z) >> 16;
      ems[3][qq] = __half2float(__ushort_as_half((unsigned short)sp.w));
      ks [3][qq] = ((int)sp.w) >> 16;
    }

#pragma unroll
    for (int i = 0; i < 2; ++i) {
#pragma unroll
      for (int j = 0; j < 4; ++j) {
        float e[4];
#pragma unroll
        for (int qq = 0; qq < 4; ++qq) {
          int kk = kt[i][qq] + ks[j][qq];
          kk = min(kk, 30);                       // den <= 2^124, no inf/NaN
          e[qq] = ldexpf(emt[i][qq] * ems[j][qq], kk);
        }
        const float a0 = e[0] + 1.0f, a1 = e[1] + 1.0f;
        const float a2 = e[2] + 1.0f, a3 = e[3] + 1.0f;
        const float p12 = a0 * a1, p34 = a2 * a3;
        float u1 = vq.x * a1; u1 = fmaf(vq.y, a0, u1);
        float u2 = vq.z * a3; u2 = fmaf(vq.w, a2, u2);
        float num = u1 * p34; num = fmaf(u2, p12, num);
        const float den = p12 * p34;
        racc[i][j] = fmaf(num, __builtin_amdgcn_rcpf(den), racc[i][j]);
      }
    }
  }

  const float c1 = sv * INV_SCALE;
  const float c2 = -2.0f * INV_SCALE;
#pragma unroll
  for (int i = 0; i < 2; ++i) {
    const int t = tbase + 2 * tg + i;
    float4 o;
    o.x = fmaf(racc[i][0], c2, c1);
    o.y = fmaf(racc[i][1], c2, c1);
    o.z = fmaf(racc[i][2], c2, c1);
    o.w = fmaf(racc[i][3], c2, c1);
    *(float4*)(out + (size_t)(b * 512 + t) * 512 + sbase + 4 * sg) = o;
  }
}

extern "C" void kernel_launch(void* const* d_in, const int* in_sizes, int n_in,
                              void* d_out, int out_size, void* d_ws, size_t ws_size,
                              hipStream_t stream) {
  const float* query = (const float*)d_in[0];  // (8,512,512)
  const float* keys  = (const float*)d_in[1];  // (8,512,512)
  const float* W1    = (const float*)d_in[2];  // (512,128) pairs with keys
  const float* W2    = (const float*)d_in[3];  // (512,128) pairs with query
  const float* v     = (const float*)d_in[4];  // (128,)
  float* out = (float*)d_out;                  // (8,512,512) fp32

  unsigned int* x1w = (unsigned int*)d_ws;     // 8*512*128 packs (2 MB)
  unsigned int* x2w = x1w + 8 * 512 * 128;     // 2 MB more

  hipLaunchKernelGGL(proj_kernel, dim3(256), dim3(512), 0, stream,
                     query, W2, keys, W1, x1w, x2w);
  hipLaunchKernelGGL(score_kernel, dim3(512), dim3(512), 0, stream,
                     x1w, x2w, v, out);
}